// Round 13
// baseline (168.085 us; speedup 1.0000x reference)
//
#include <hip/hip_runtime.h>
#include <hip/hip_fp16.h>
#include <math.h>

#define IN_DIM   128
#define OUT_DIM  128
#define FEAT_DIM 64
#define NB       64     // nodes per k_linear block
#define SCH      256    // scan chunk size == dsts per bucket

__device__ __forceinline__ float2 h2f2(unsigned u) {
    __half2 h = *reinterpret_cast<const __half2*>(&u);
    return __half22float2(h);
}
__device__ __forceinline__ unsigned f2h2(float a, float b) {
    __half2 h = __floats2half2_rn(a, b);
    return *reinterpret_cast<unsigned*>(&h);
}

// ---------------------------------------------------------------------------
// z = fp16(h @ W_fc) ; dz = feat @ W_dst.  256 threads/block, 64 nodes/block.
// Grid = 2*nbz blocks: first nbz do z, rest do dz.  LDS = 16 KB both branches
// (h tile staged as FP16) => 10 blocks/CU, whole grid resident in one round.
// ---------------------------------------------------------------------------
__global__ __launch_bounds__(256) void k_linear(
        const float* __restrict__ h, const float* __restrict__ feat,
        const float* __restrict__ Wfc, const float* __restrict__ Wdst,
        unsigned short* __restrict__ z_h, float* __restrict__ dz, int N, int nbz) {
    int t  = threadIdx.x;        // 0..255
    int c  = t & 31;             // cols 4c..4c+3
    int j0 = t >> 5;             // 0..7 -> nodes n0 + 8*j0 + jj
    int b  = blockIdx.x;
    bool do_z = (b < nbz);
    int n0 = (do_z ? b : b - nbz) * NB;

    __shared__ char smem[NB * 256];   // 16 KB

    float4 acc[8];
#pragma unroll
    for (int jj = 0; jj < 8; ++jj) acc[jj] = make_float4(0.f, 0.f, 0.f, 0.f);

    if (do_z) {
        // stage h tile as fp16: [node][32] uint2, each uint2 = 4 consecutive k
        uint2* sh = (uint2*)smem;
        for (int i = t; i < NB * 32; i += 256) {
            int row = i >> 5, col = i & 31;
            int n = min(n0 + row, N - 1);
            float4 v = ((const float4*)(h + (size_t)n * IN_DIM))[col];
            sh[i] = make_uint2(f2h2(v.x, v.y), f2h2(v.z, v.w));
        }
        __syncthreads();

        const float4* Wf4 = (const float4*)Wfc;
#pragma unroll 2
        for (int k4 = 0; k4 < IN_DIM / 4; ++k4) {
            float4 w0 = Wf4[(size_t)(4 * k4 + 0) * 32 + c];
            float4 w1 = Wf4[(size_t)(4 * k4 + 1) * 32 + c];
            float4 w2 = Wf4[(size_t)(4 * k4 + 2) * 32 + c];
            float4 w3 = Wf4[(size_t)(4 * k4 + 3) * 32 + c];
#pragma unroll
            for (int jj = 0; jj < 8; ++jj) {
                uint2 q = sh[(j0 * 8 + jj) * 32 + k4];
                float2 f01 = h2f2(q.x), f23 = h2f2(q.y);
                acc[jj].x += f01.x * w0.x + f01.y * w1.x + f23.x * w2.x + f23.y * w3.x;
                acc[jj].y += f01.x * w0.y + f01.y * w1.y + f23.x * w2.y + f23.y * w3.y;
                acc[jj].z += f01.x * w0.z + f01.y * w1.z + f23.x * w2.z + f23.y * w3.z;
                acc[jj].w += f01.x * w0.w + f01.y * w1.w + f23.x * w2.w + f23.y * w3.w;
            }
        }
#pragma unroll
        for (int jj = 0; jj < 8; ++jj) {
            int n = n0 + j0 * 8 + jj;
            if (n < N) {
                uint2 pk = make_uint2(f2h2(acc[jj].x, acc[jj].y),
                                      f2h2(acc[jj].z, acc[jj].w));
                ((uint2*)(z_h + (size_t)n * OUT_DIM))[c] = pk;
            }
        }
    } else {
        float4* s = (float4*)smem;   // feat tile fp32: [node][16] float4
        for (int i = t; i < NB * 16; i += 256) {
            int row = i >> 4, col = i & 15;
            int n = min(n0 + row, N - 1);
            s[i] = ((const float4*)(feat + (size_t)n * FEAT_DIM))[col];
        }
        __syncthreads();

        const float4* Wd4 = (const float4*)Wdst;
#pragma unroll 2
        for (int k4 = 0; k4 < FEAT_DIM / 4; ++k4) {
            float4 w0 = Wd4[(size_t)(4 * k4 + 0) * 32 + c];
            float4 w1 = Wd4[(size_t)(4 * k4 + 1) * 32 + c];
            float4 w2 = Wd4[(size_t)(4 * k4 + 2) * 32 + c];
            float4 w3 = Wd4[(size_t)(4 * k4 + 3) * 32 + c];
#pragma unroll
            for (int jj = 0; jj < 8; ++jj) {
                float4 fv = s[(j0 * 8 + jj) * 16 + k4];
                acc[jj].x += fv.x * w0.x + fv.y * w1.x + fv.z * w2.x + fv.w * w3.x;
                acc[jj].y += fv.x * w0.y + fv.y * w1.y + fv.z * w2.y + fv.w * w3.y;
                acc[jj].z += fv.x * w0.z + fv.y * w1.z + fv.z * w2.z + fv.w * w3.z;
                acc[jj].w += fv.x * w0.w + fv.y * w1.w + fv.z * w2.w + fv.w * w3.w;
            }
        }
#pragma unroll
        for (int jj = 0; jj < 8; ++jj) {
            int n = n0 + j0 * 8 + jj;
            if (n < N) ((float4*)(dz + (size_t)n * OUT_DIM))[c] = acc[jj];
        }
    }
}

// ---------------------------------------------------------------------------
// CSR build: histogram -> scan -> bucketed counting sort (k_bin + k_sort)
// ---------------------------------------------------------------------------
__global__ void k_hist(const int* __restrict__ dst, unsigned* __restrict__ counts, int E) {
    for (int i = blockIdx.x * blockDim.x + threadIdx.x; i < E; i += gridDim.x * blockDim.x)
        atomicAdd(&counts[dst[i]], 1u);
}

__global__ __launch_bounds__(SCH) void k_scan1(const unsigned* __restrict__ counts,
                                               unsigned* __restrict__ partials, int N) {
    int b = blockIdx.x, t = threadIdx.x;
    int idx = b * SCH + t;
    unsigned v = (idx < N) ? counts[idx] : 0u;
#pragma unroll
    for (int off = 32; off; off >>= 1) v += __shfl_xor(v, off);   // wave64 reduce
    __shared__ unsigned sw[SCH / 64];
    if ((t & 63) == 0) sw[t >> 6] = v;
    __syncthreads();
    if (t == 0) {
        unsigned s = 0;
#pragma unroll
        for (int i = 0; i < SCH / 64; ++i) s += sw[i];
        partials[b] = s;
    }
}

__global__ __launch_bounds__(1024) void k_scan2(unsigned* __restrict__ partials, int nblk) {
    __shared__ unsigned s[1024];
    int t = threadIdx.x;
    unsigned v = (t < nblk) ? partials[t] : 0u;
    s[t] = v;
    __syncthreads();
    for (int off = 1; off < 1024; off <<= 1) {
        unsigned u = (t >= off) ? s[t - off] : 0u;
        __syncthreads();
        s[t] += u;
        __syncthreads();
    }
    if (t < nblk) partials[t] = s[t] - v;
}

// also seeds bucket_cursor[b] = offsets[b*256]
__global__ __launch_bounds__(SCH) void k_scan3(const unsigned* __restrict__ counts,
                                               const unsigned* __restrict__ partials,
                                               unsigned* __restrict__ offsets,
                                               unsigned* __restrict__ bucket_cursor, int N) {
    int b = blockIdx.x, t = threadIdx.x;
    int idx = b * SCH + t;
    unsigned v = (idx < N) ? counts[idx] : 0u;
    __shared__ unsigned s[SCH];
    s[t] = v;
    __syncthreads();
    for (int off = 1; off < SCH; off <<= 1) {
        unsigned u = (t >= off) ? s[t - off] : 0u;
        __syncthreads();
        s[t] += u;
        __syncthreads();
    }
    unsigned base = partials[b];
    if (idx < N)  offsets[idx] = base + s[t] - v;
    if (idx == N - 1) offsets[N] = base + s[t];
    if (t == 0) bucket_cursor[b] = base;
}

// counting sort stage 1: bin edges by bucket (dst>>8); payload packed u32:
// src (24 bits) | local-dst (8 bits) << 24.  Line-filling grouped writes.
__global__ __launch_bounds__(256) void k_bin(
        const int* __restrict__ dst, const int* __restrict__ src,
        unsigned* __restrict__ bucket_cursor, unsigned* __restrict__ binned,
        int E, int nbkt) {
    __shared__ unsigned hist[256];
    __shared__ unsigned base[256];
    __shared__ unsigned cur[256];
    int t = threadIdx.x;
    int per = (E + gridDim.x - 1) / gridDim.x;
    int lo = blockIdx.x * per;
    int hi = min(E, lo + per);

    hist[t] = 0;
    cur[t]  = 0;
    __syncthreads();
    for (int i = lo + t; i < hi; i += 256)
        atomicAdd(&hist[dst[i] >> 8], 1u);
    __syncthreads();
    if (t < nbkt) base[t] = atomicAdd(&bucket_cursor[t], hist[t]);
    __syncthreads();
    for (int i = lo + t; i < hi; i += 256) {
        int d = dst[i];
        int bk = d >> 8;
        unsigned slot = base[bk] + atomicAdd(&cur[bk], 1u);
        binned[slot] = (unsigned)src[i] | ((unsigned)(d & 255) << 24);
    }
}

// counting sort stage 2: block b owns dst range [b*256, +256) + its csr window
__global__ __launch_bounds__(256) void k_sort(
        const unsigned* __restrict__ binned, const unsigned* __restrict__ offsets,
        unsigned* __restrict__ csr, int N) {
    __shared__ unsigned off[257];
    __shared__ unsigned cur[256];
    int b = blockIdx.x, t = threadIdx.x;
    int d0 = b << 8;
    int nd = min(N - d0, 256);
    if (t < nd) off[t] = offsets[d0 + t];
    if (t == 0) off[nd] = offsets[d0 + nd];
    cur[t] = 0;
    __syncthreads();
    unsigned lo = off[0], hi = off[nd];
    for (unsigned i = lo + t; i < hi; i += 256) {
        unsigned e = binned[i];
        int ld = (int)(e >> 24);
        unsigned pos = off[ld] + atomicAdd(&cur[ld], 1u);
        csr[pos] = e & 0xFFFFFFu;
    }
}

// ---------------------------------------------------------------------------
// Fused attention + aggregation. One 64-lane wave per node (4 nodes/block).
// 16 lanes per edge; z rows gathered in FP16 (256 B/row, one uint4/lane),
// unpacked to fp32 for dot + accumulate. dz stays fp32.
// ---------------------------------------------------------------------------
__global__ __launch_bounds__(256) void k_node(
        const unsigned short* __restrict__ z_h, const float* __restrict__ dz,
        const unsigned* __restrict__ offsets, const unsigned* __restrict__ csr,
        float* __restrict__ out, int N) {
    int lane = threadIdx.x & 63;
    int wv   = threadIdx.x >> 6;          // 0..3
    int g    = lane >> 4;                 // edge slot 0..3
    int l16  = lane & 15;                 // row chunk: dims [8*l16, 8*l16+8)
    int n = blockIdx.x * 4 + wv;
    if (n >= N) return;

    unsigned start = offsets[n];
    int deg = (int)(offsets[n + 1] - start);
    float4* orow = (float4*)(out + (size_t)n * OUT_DIM);
    if (deg == 0) {
        if (g == 0) {
            orow[2 * l16]     = make_float4(0.f, 0.f, 0.f, 0.f);
            orow[2 * l16 + 1] = make_float4(0.f, 0.f, 0.f, 0.f);
        }
        return;
    }

    const float4* dzp = (const float4*)(dz + (size_t)n * OUT_DIM);
    float4 d0 = dzp[2 * l16];
    float4 d1 = dzp[2 * l16 + 1];

    float a[8];
#pragma unroll
    for (int k = 0; k < 8; ++k) a[k] = 0.f;
    float denom = 0.f;

    for (int i = 0; i < deg; i += 8) {
        int eA = i + g;
        int eB = i + 4 + g;
        bool vA = eA < deg;
        bool vB = eB < deg;
        int sA = vA ? (int)csr[start + eA] : 0;
        int sB = vB ? (int)csr[start + eB] : 0;
        uint4 qA = ((const uint4*)(z_h + (size_t)sA * OUT_DIM))[l16];
        uint4 qB = ((const uint4*)(z_h + (size_t)sB * OUT_DIM))[l16];

        float2 zA01 = h2f2(qA.x), zA23 = h2f2(qA.y), zA45 = h2f2(qA.z), zA67 = h2f2(qA.w);
        float2 zB01 = h2f2(qB.x), zB23 = h2f2(qB.y), zB45 = h2f2(qB.z), zB67 = h2f2(qB.w);

        float pA = zA01.x * d0.x + zA01.y * d0.y + zA23.x * d0.z + zA23.y * d0.w
                 + zA45.x * d1.x + zA45.y * d1.y + zA67.x * d1.z + zA67.y * d1.w;
        float pB = zB01.x * d0.x + zB01.y * d0.y + zB23.x * d0.z + zB23.y * d0.w
                 + zB45.x * d1.x + zB45.y * d1.y + zB67.x * d1.z + zB67.y * d1.w;
#pragma unroll
        for (int off = 1; off <= 8; off <<= 1) {   // reduce within 16-lane group
            pA += __shfl_xor(pA, off);
            pB += __shfl_xor(pB, off);
        }
        float wA = vA ? __expf(pA) : 0.f;
        float wB = vB ? __expf(pB) : 0.f;
        denom += wA + wB;
        a[0] += wA * zA01.x + wB * zB01.x;  a[1] += wA * zA01.y + wB * zB01.y;
        a[2] += wA * zA23.x + wB * zB23.x;  a[3] += wA * zA23.y + wB * zB23.y;
        a[4] += wA * zA45.x + wB * zB45.x;  a[5] += wA * zA45.y + wB * zB45.y;
        a[6] += wA * zA67.x + wB * zB67.x;  a[7] += wA * zA67.y + wB * zB67.y;
    }

    // fold the 4 edge-groups together (lanes l, l^16, l^32, l^48)
#pragma unroll
    for (int off = 16; off <= 32; off <<= 1) {
#pragma unroll
        for (int k = 0; k < 8; ++k) a[k] += __shfl_xor(a[k], off);
        denom += __shfl_xor(denom, off);
    }

    if (g == 0) {
        float inv = 1.f / denom;
        orow[2 * l16]     = make_float4(a[0] * inv, a[1] * inv, a[2] * inv, a[3] * inv);
        orow[2 * l16 + 1] = make_float4(a[4] * inv, a[5] * inv, a[6] * inv, a[7] * inv);
    }
}

// ---------------------------------------------------------------------------
extern "C" void kernel_launch(void* const* d_in, const int* in_sizes, int n_in,
                              void* d_out, int out_size, void* d_ws, size_t ws_size,
                              hipStream_t stream) {
    const float* h    = (const float*)d_in[0];
    const float* feat = (const float*)d_in[1];
    const float* Wfc  = (const float*)d_in[2];
    const float* Wdst = (const float*)d_in[3];
    const int*   src  = (const int*)d_in[4];
    const int*   dst  = (const int*)d_in[5];
    float*       out  = (float*)d_out;

    int N = in_sizes[0] / IN_DIM;
    int E = in_sizes[4];

    char* ws = (char*)d_ws;
    unsigned short* z_h = (unsigned short*)ws; ws += (size_t)N * OUT_DIM * sizeof(unsigned short);
    float*    dz       = (float*)ws;    ws += (size_t)N * OUT_DIM * sizeof(float);
    unsigned* binned   = (unsigned*)ws; ws += (size_t)E * sizeof(unsigned);
    unsigned* counts   = (unsigned*)ws; ws += (size_t)N * sizeof(unsigned);
    unsigned* offsets  = (unsigned*)ws; ws += (size_t)(N + 1) * sizeof(unsigned);
    unsigned* partials = (unsigned*)ws; ws += (size_t)1024 * sizeof(unsigned);
    unsigned* bcursor  = (unsigned*)ws; ws += (size_t)1024 * sizeof(unsigned);
    unsigned* csr      = (unsigned*)ws;

    int nbz  = (N + NB - 1) / NB;       // 782
    int nblk = (N + SCH - 1) / SCH;     // 196 buckets

    hipMemsetAsync(counts, 0, (size_t)N * sizeof(unsigned), stream);

    k_linear <<<2 * nbz, 256, 0, stream>>>(h, feat, Wfc, Wdst, z_h, dz, N, nbz);
    k_hist   <<<1024, 256, 0, stream>>>(dst, counts, E);
    k_scan1  <<<nblk, SCH, 0, stream>>>(counts, partials, N);
    k_scan2  <<<1, 1024, 0, stream>>>(partials, nblk);
    k_scan3  <<<nblk, SCH, 0, stream>>>(counts, partials, offsets, bcursor, N);
    k_bin    <<<512, 256, 0, stream>>>(dst, src, bcursor, binned, E, nblk);
    k_sort   <<<nblk, 256, 0, stream>>>(binned, offsets, csr, N);
    k_node   <<<(N + 3) / 4, 256, 0, stream>>>(z_h, dz, offsets, csr, out, N);
}

// Round 14
// 155.445 us; speedup vs baseline: 1.0813x; 1.0813x over previous
//
#include <hip/hip_runtime.h>
#include <hip/hip_fp16.h>
#include <math.h>

#define IN_DIM   128
#define OUT_DIM  128
#define FEAT_DIM 64
#define NB       64     // nodes per k_linear block
#define SCH      256    // scan chunk size == dsts per bucket

typedef _Float16 h2v __attribute__((ext_vector_type(2)));

__device__ __forceinline__ float2 h2f2(unsigned u) {
    __half2 h = *reinterpret_cast<const __half2*>(&u);
    return __half22float2(h);
}
__device__ __forceinline__ unsigned f2h2(float a, float b) {
    __half2 h = __floats2half2_rn(a, b);
    return *reinterpret_cast<unsigned*>(&h);
}
// c += dot(half2 a, half2 b) with fp32 accumulate (V_DOT2_F32_F16)
__device__ __forceinline__ float dot2(unsigned a, unsigned b, float c) {
#if __has_builtin(__builtin_amdgcn_fdot2)
    return __builtin_amdgcn_fdot2(*reinterpret_cast<h2v*>(&a),
                                  *reinterpret_cast<h2v*>(&b), c, false);
#else
    float2 fa = h2f2(a), fb = h2f2(b);
    return c + fa.x * fb.x + fa.y * fb.y;
#endif
}

// ---------------------------------------------------------------------------
// k_wt: pack W_fc / W_dst as fp16 k-pairs.  Wfp[k2][c] = half2(W[2k2][c],
// W[2k2+1][c]).  Wfp: 64x128 u32 = 32 KB (L1-resident), Wdp: 32x128 = 16 KB.
// ---------------------------------------------------------------------------
__global__ __launch_bounds__(256) void k_wt(const float* __restrict__ Wfc,
                                            const float* __restrict__ Wdst,
                                            unsigned* __restrict__ Wfp,
                                            unsigned* __restrict__ Wdp) {
    int idx = blockIdx.x * 256 + threadIdx.x;       // 48 blocks
    if (idx < 8192) {               // 64 k2 x 128 c
        int k2 = idx >> 7, c = idx & 127;
        Wfp[idx] = f2h2(Wfc[(2 * k2) * 128 + c], Wfc[(2 * k2 + 1) * 128 + c]);
    } else if (idx < 12288) {       // 32 k2 x 128 c
        int i2 = idx - 8192;
        int k2 = i2 >> 7, c = i2 & 127;
        Wdp[i2] = f2h2(Wdst[(2 * k2) * 128 + c], Wdst[(2 * k2 + 1) * 128 + c]);
    }
}

// ---------------------------------------------------------------------------
// z = fp16(h @ W_fc) ; dz = feat @ W_dst — both via v_dot2_f32_f16.
// 256 threads/block, 64 nodes/block; grid = 2*nbz (z blocks, then dz blocks).
// h/feat tiles staged fp16 in LDS; W read as packed uint4 (4 cols x 1 k-pair).
// ---------------------------------------------------------------------------
__global__ __launch_bounds__(256) void k_linear(
        const float* __restrict__ h, const float* __restrict__ feat,
        const unsigned* __restrict__ Wfp, const unsigned* __restrict__ Wdp,
        unsigned short* __restrict__ z_h, float* __restrict__ dz, int N, int nbz) {
    int t  = threadIdx.x;        // 0..255
    int c  = t & 31;             // cols 4c..4c+3
    int j0 = t >> 5;             // 0..7 -> nodes n0 + 8*j0 + jj
    int b  = blockIdx.x;
    bool do_z = (b < nbz);
    int n0 = (do_z ? b : b - nbz) * NB;

    __shared__ uint2 sh[NB * 32];   // 16 KB max (z); dz uses half

    float4 acc[8];
#pragma unroll
    for (int jj = 0; jj < 8; ++jj) acc[jj] = make_float4(0.f, 0.f, 0.f, 0.f);

    if (do_z) {
        // stage h tile fp16: [node][32] uint2 (uint2 = 2 k-pairs = 4 k)
        for (int i = t; i < NB * 32; i += 256) {
            int row = i >> 5, col = i & 31;
            int n = min(n0 + row, N - 1);
            float4 v = ((const float4*)(h + (size_t)n * IN_DIM))[col];
            sh[i] = make_uint2(f2h2(v.x, v.y), f2h2(v.z, v.w));
        }
        __syncthreads();

        const uint4* Wp4 = (const uint4*)Wfp;   // [k2][32] uint4
#pragma unroll 2
        for (int k4 = 0; k4 < 32; ++k4) {
            uint4 wA = Wp4[(size_t)(2 * k4) * 32 + c];       // k-pair 2k4
            uint4 wB = Wp4[(size_t)(2 * k4 + 1) * 32 + c];   // k-pair 2k4+1
#pragma unroll
            for (int jj = 0; jj < 8; ++jj) {
                uint2 q = sh[(j0 * 8 + jj) * 32 + k4];
                acc[jj].x = dot2(q.y, wB.x, dot2(q.x, wA.x, acc[jj].x));
                acc[jj].y = dot2(q.y, wB.y, dot2(q.x, wA.y, acc[jj].y));
                acc[jj].z = dot2(q.y, wB.z, dot2(q.x, wA.z, acc[jj].z));
                acc[jj].w = dot2(q.y, wB.w, dot2(q.x, wA.w, acc[jj].w));
            }
        }
#pragma unroll
        for (int jj = 0; jj < 8; ++jj) {
            int n = n0 + j0 * 8 + jj;
            if (n < N) {
                uint2 pk = make_uint2(f2h2(acc[jj].x, acc[jj].y),
                                      f2h2(acc[jj].z, acc[jj].w));
                ((uint2*)(z_h + (size_t)n * OUT_DIM))[c] = pk;
            }
        }
    } else {
        // stage feat tile fp16: [node][16] uint2
        for (int i = t; i < NB * 16; i += 256) {
            int row = i >> 4, col = i & 15;
            int n = min(n0 + row, N - 1);
            float4 v = ((const float4*)(feat + (size_t)n * FEAT_DIM))[col];
            sh[i] = make_uint2(f2h2(v.x, v.y), f2h2(v.z, v.w));
        }
        __syncthreads();

        const uint4* Wd4 = (const uint4*)Wdp;   // [k2][32] uint4
#pragma unroll 2
        for (int k4 = 0; k4 < 16; ++k4) {
            uint4 wA = Wd4[(size_t)(2 * k4) * 32 + c];
            uint4 wB = Wd4[(size_t)(2 * k4 + 1) * 32 + c];
#pragma unroll
            for (int jj = 0; jj < 8; ++jj) {
                uint2 q = sh[(j0 * 8 + jj) * 16 + k4];
                acc[jj].x = dot2(q.y, wB.x, dot2(q.x, wA.x, acc[jj].x));
                acc[jj].y = dot2(q.y, wB.y, dot2(q.x, wA.y, acc[jj].y));
                acc[jj].z = dot2(q.y, wB.z, dot2(q.x, wA.z, acc[jj].z));
                acc[jj].w = dot2(q.y, wB.w, dot2(q.x, wA.w, acc[jj].w));
            }
        }
#pragma unroll
        for (int jj = 0; jj < 8; ++jj) {
            int n = n0 + j0 * 8 + jj;
            if (n < N) ((float4*)(dz + (size_t)n * OUT_DIM))[c] = acc[jj];
        }
    }
}

// ---------------------------------------------------------------------------
// CSR build: histogram -> scan -> bucketed counting sort (k_bin + k_sort)
// ---------------------------------------------------------------------------
__global__ void k_hist(const int* __restrict__ dst, unsigned* __restrict__ counts, int E) {
    for (int i = blockIdx.x * blockDim.x + threadIdx.x; i < E; i += gridDim.x * blockDim.x)
        atomicAdd(&counts[dst[i]], 1u);
}

__global__ __launch_bounds__(SCH) void k_scan1(const unsigned* __restrict__ counts,
                                               unsigned* __restrict__ partials, int N) {
    int b = blockIdx.x, t = threadIdx.x;
    int idx = b * SCH + t;
    unsigned v = (idx < N) ? counts[idx] : 0u;
#pragma unroll
    for (int off = 32; off; off >>= 1) v += __shfl_xor(v, off);   // wave64 reduce
    __shared__ unsigned sw[SCH / 64];
    if ((t & 63) == 0) sw[t >> 6] = v;
    __syncthreads();
    if (t == 0) {
        unsigned s = 0;
#pragma unroll
        for (int i = 0; i < SCH / 64; ++i) s += sw[i];
        partials[b] = s;
    }
}

__global__ __launch_bounds__(1024) void k_scan2(unsigned* __restrict__ partials, int nblk) {
    __shared__ unsigned s[1024];
    int t = threadIdx.x;
    unsigned v = (t < nblk) ? partials[t] : 0u;
    s[t] = v;
    __syncthreads();
    for (int off = 1; off < 1024; off <<= 1) {
        unsigned u = (t >= off) ? s[t - off] : 0u;
        __syncthreads();
        s[t] += u;
        __syncthreads();
    }
    if (t < nblk) partials[t] = s[t] - v;
}

// also seeds bucket_cursor[b] = offsets[b*256]
__global__ __launch_bounds__(SCH) void k_scan3(const unsigned* __restrict__ counts,
                                               const unsigned* __restrict__ partials,
                                               unsigned* __restrict__ offsets,
                                               unsigned* __restrict__ bucket_cursor, int N) {
    int b = blockIdx.x, t = threadIdx.x;
    int idx = b * SCH + t;
    unsigned v = (idx < N) ? counts[idx] : 0u;
    __shared__ unsigned s[SCH];
    s[t] = v;
    __syncthreads();
    for (int off = 1; off < SCH; off <<= 1) {
        unsigned u = (t >= off) ? s[t - off] : 0u;
        __syncthreads();
        s[t] += u;
        __syncthreads();
    }
    unsigned base = partials[b];
    if (idx < N)  offsets[idx] = base + s[t] - v;
    if (idx == N - 1) offsets[N] = base + s[t];
    if (t == 0) bucket_cursor[b] = base;
}

// counting sort stage 1: bin edges by bucket (dst>>8); payload packed u32:
// src (24 bits) | local-dst (8 bits) << 24.  Line-filling grouped writes.
__global__ __launch_bounds__(256) void k_bin(
        const int* __restrict__ dst, const int* __restrict__ src,
        unsigned* __restrict__ bucket_cursor, unsigned* __restrict__ binned,
        int E, int nbkt) {
    __shared__ unsigned hist[256];
    __shared__ unsigned base[256];
    __shared__ unsigned cur[256];
    int t = threadIdx.x;
    int per = (E + gridDim.x - 1) / gridDim.x;
    int lo = blockIdx.x * per;
    int hi = min(E, lo + per);

    hist[t] = 0;
    cur[t]  = 0;
    __syncthreads();
    for (int i = lo + t; i < hi; i += 256)
        atomicAdd(&hist[dst[i] >> 8], 1u);
    __syncthreads();
    if (t < nbkt) base[t] = atomicAdd(&bucket_cursor[t], hist[t]);
    __syncthreads();
    for (int i = lo + t; i < hi; i += 256) {
        int d = dst[i];
        int bk = d >> 8;
        unsigned slot = base[bk] + atomicAdd(&cur[bk], 1u);
        binned[slot] = (unsigned)src[i] | ((unsigned)(d & 255) << 24);
    }
}

// counting sort stage 2: block b owns dst range [b*256, +256) + its csr window
__global__ __launch_bounds__(256) void k_sort(
        const unsigned* __restrict__ binned, const unsigned* __restrict__ offsets,
        unsigned* __restrict__ csr, int N) {
    __shared__ unsigned off[257];
    __shared__ unsigned cur[256];
    int b = blockIdx.x, t = threadIdx.x;
    int d0 = b << 8;
    int nd = min(N - d0, 256);
    if (t < nd) off[t] = offsets[d0 + t];
    if (t == 0) off[nd] = offsets[d0 + nd];
    cur[t] = 0;
    __syncthreads();
    unsigned lo = off[0], hi = off[nd];
    for (unsigned i = lo + t; i < hi; i += 256) {
        unsigned e = binned[i];
        int ld = (int)(e >> 24);
        unsigned pos = off[ld] + atomicAdd(&cur[ld], 1u);
        csr[pos] = e & 0xFFFFFFu;
    }
}

// ---------------------------------------------------------------------------
// Fused attention + aggregation. One 64-lane wave per node (4 nodes/block).
// 16 lanes per edge; z rows gathered in FP16 (256 B/row, one uint4/lane),
// unpacked to fp32 for dot + accumulate. dz stays fp32.
// ---------------------------------------------------------------------------
__global__ __launch_bounds__(256) void k_node(
        const unsigned short* __restrict__ z_h, const float* __restrict__ dz,
        const unsigned* __restrict__ offsets, const unsigned* __restrict__ csr,
        float* __restrict__ out, int N) {
    int lane = threadIdx.x & 63;
    int wv   = threadIdx.x >> 6;          // 0..3
    int g    = lane >> 4;                 // edge slot 0..3
    int l16  = lane & 15;                 // row chunk: dims [8*l16, 8*l16+8)
    int n = blockIdx.x * 4 + wv;
    if (n >= N) return;

    unsigned start = offsets[n];
    int deg = (int)(offsets[n + 1] - start);
    float4* orow = (float4*)(out + (size_t)n * OUT_DIM);
    if (deg == 0) {
        if (g == 0) {
            orow[2 * l16]     = make_float4(0.f, 0.f, 0.f, 0.f);
            orow[2 * l16 + 1] = make_float4(0.f, 0.f, 0.f, 0.f);
        }
        return;
    }

    const float4* dzp = (const float4*)(dz + (size_t)n * OUT_DIM);
    float4 d0 = dzp[2 * l16];
    float4 d1 = dzp[2 * l16 + 1];

    float a[8];
#pragma unroll
    for (int k = 0; k < 8; ++k) a[k] = 0.f;
    float denom = 0.f;

    for (int i = 0; i < deg; i += 8) {
        int eA = i + g;
        int eB = i + 4 + g;
        bool vA = eA < deg;
        bool vB = eB < deg;
        int sA = vA ? (int)csr[start + eA] : 0;
        int sB = vB ? (int)csr[start + eB] : 0;
        uint4 qA = ((const uint4*)(z_h + (size_t)sA * OUT_DIM))[l16];
        uint4 qB = ((const uint4*)(z_h + (size_t)sB * OUT_DIM))[l16];

        float2 zA01 = h2f2(qA.x), zA23 = h2f2(qA.y), zA45 = h2f2(qA.z), zA67 = h2f2(qA.w);
        float2 zB01 = h2f2(qB.x), zB23 = h2f2(qB.y), zB45 = h2f2(qB.z), zB67 = h2f2(qB.w);

        float pA = zA01.x * d0.x + zA01.y * d0.y + zA23.x * d0.z + zA23.y * d0.w
                 + zA45.x * d1.x + zA45.y * d1.y + zA67.x * d1.z + zA67.y * d1.w;
        float pB = zB01.x * d0.x + zB01.y * d0.y + zB23.x * d0.z + zB23.y * d0.w
                 + zB45.x * d1.x + zB45.y * d1.y + zB67.x * d1.z + zB67.y * d1.w;
#pragma unroll
        for (int off = 1; off <= 8; off <<= 1) {   // reduce within 16-lane group
            pA += __shfl_xor(pA, off);
            pB += __shfl_xor(pB, off);
        }
        float wA = vA ? __expf(pA) : 0.f;
        float wB = vB ? __expf(pB) : 0.f;
        denom += wA + wB;
        a[0] += wA * zA01.x + wB * zB01.x;  a[1] += wA * zA01.y + wB * zB01.y;
        a[2] += wA * zA23.x + wB * zB23.x;  a[3] += wA * zA23.y + wB * zB23.y;
        a[4] += wA * zA45.x + wB * zB45.x;  a[5] += wA * zA45.y + wB * zB45.y;
        a[6] += wA * zA67.x + wB * zB67.x;  a[7] += wA * zA67.y + wB * zB67.y;
    }

    // fold the 4 edge-groups together (lanes l, l^16, l^32, l^48)
#pragma unroll
    for (int off = 16; off <= 32; off <<= 1) {
#pragma unroll
        for (int k = 0; k < 8; ++k) a[k] += __shfl_xor(a[k], off);
        denom += __shfl_xor(denom, off);
    }

    if (g == 0) {
        float inv = 1.f / denom;
        orow[2 * l16]     = make_float4(a[0] * inv, a[1] * inv, a[2] * inv, a[3] * inv);
        orow[2 * l16 + 1] = make_float4(a[4] * inv, a[5] * inv, a[6] * inv, a[7] * inv);
    }
}

// ---------------------------------------------------------------------------
extern "C" void kernel_launch(void* const* d_in, const int* in_sizes, int n_in,
                              void* d_out, int out_size, void* d_ws, size_t ws_size,
                              hipStream_t stream) {
    const float* h    = (const float*)d_in[0];
    const float* feat = (const float*)d_in[1];
    const float* Wfc  = (const float*)d_in[2];
    const float* Wdst = (const float*)d_in[3];
    const int*   src  = (const int*)d_in[4];
    const int*   dst  = (const int*)d_in[5];
    float*       out  = (float*)d_out;

    int N = in_sizes[0] / IN_DIM;
    int E = in_sizes[4];

    char* ws = (char*)d_ws;
    unsigned short* z_h = (unsigned short*)ws; ws += (size_t)N * OUT_DIM * sizeof(unsigned short);
    float*    dz       = (float*)ws;    ws += (size_t)N * OUT_DIM * sizeof(float);
    unsigned* Wfp      = (unsigned*)ws; ws += (size_t)8192 * sizeof(unsigned);
    unsigned* Wdp      = (unsigned*)ws; ws += (size_t)4096 * sizeof(unsigned);
    unsigned* binned   = (unsigned*)ws; ws += (size_t)E * sizeof(unsigned);
    unsigned* counts   = (unsigned*)ws; ws += (size_t)N * sizeof(unsigned);
    unsigned* offsets  = (unsigned*)ws; ws += (size_t)(N + 1) * sizeof(unsigned);
    unsigned* partials = (unsigned*)ws; ws += (size_t)1024 * sizeof(unsigned);
    unsigned* bcursor  = (unsigned*)ws; ws += (size_t)1024 * sizeof(unsigned);
    unsigned* csr      = (unsigned*)ws;

    int nbz  = (N + NB - 1) / NB;       // 782
    int nblk = (N + SCH - 1) / SCH;     // 196 buckets

    hipMemsetAsync(counts, 0, (size_t)N * sizeof(unsigned), stream);

    k_wt     <<<48, 256, 0, stream>>>(Wfc, Wdst, Wfp, Wdp);
    k_linear <<<2 * nbz, 256, 0, stream>>>(h, feat, Wfp, Wdp, z_h, dz, N, nbz);
    k_hist   <<<1024, 256, 0, stream>>>(dst, counts, E);
    k_scan1  <<<nblk, SCH, 0, stream>>>(counts, partials, N);
    k_scan2  <<<1, 1024, 0, stream>>>(partials, nblk);
    k_scan3  <<<nblk, SCH, 0, stream>>>(counts, partials, offsets, bcursor, N);
    k_bin    <<<512, 256, 0, stream>>>(dst, src, bcursor, binned, E, nblk);
    k_sort   <<<nblk, 256, 0, stream>>>(binned, offsets, csr, N);
    k_node   <<<(N + 3) / 4, 256, 0, stream>>>(z_h, dz, offsets, csr, out, N);
}

// Round 15
// 143.013 us; speedup vs baseline: 1.1753x; 1.0869x over previous
//
#include <hip/hip_runtime.h>
#include <hip/hip_fp16.h>
#include <math.h>

#define IN_DIM   128
#define OUT_DIM  128
#define FEAT_DIM 64
#define NB       64     // nodes per k_linear block
#define SCH      256    // scan chunk size == dsts per bucket

typedef _Float16 h2v __attribute__((ext_vector_type(2)));

__device__ __forceinline__ float2 h2f2(unsigned u) {
    __half2 h = *reinterpret_cast<const __half2*>(&u);
    return __half22float2(h);
}
__device__ __forceinline__ unsigned f2h2(float a, float b) {
    __half2 h = __floats2half2_rn(a, b);
    return *reinterpret_cast<unsigned*>(&h);
}
// c += dot(half2 a, half2 b) with fp32 accumulate (V_DOT2_F32_F16)
__device__ __forceinline__ float dot2(unsigned a, unsigned b, float c) {
#if __has_builtin(__builtin_amdgcn_fdot2)
    return __builtin_amdgcn_fdot2(*reinterpret_cast<h2v*>(&a),
                                  *reinterpret_cast<h2v*>(&b), c, false);
#else
    float2 fa = h2f2(a), fb = h2f2(b);
    return c + fa.x * fb.x + fa.y * fb.y;
#endif
}

// ---------------------------------------------------------------------------
// k_wt: pack W_fc / W_dst as fp16 k-pairs.  Wfp[k2][c] = half2(W[2k2][c],
// W[2k2+1][c]).  Wfp: 64x128 u32 = 32 KB (L1-resident), Wdp: 32x128 = 16 KB.
// ---------------------------------------------------------------------------
__global__ __launch_bounds__(256) void k_wt(const float* __restrict__ Wfc,
                                            const float* __restrict__ Wdst,
                                            unsigned* __restrict__ Wfp,
                                            unsigned* __restrict__ Wdp) {
    int idx = blockIdx.x * 256 + threadIdx.x;       // 48 blocks
    if (idx < 8192) {               // 64 k2 x 128 c
        int k2 = idx >> 7, c = idx & 127;
        Wfp[idx] = f2h2(Wfc[(2 * k2) * 128 + c], Wfc[(2 * k2 + 1) * 128 + c]);
    } else if (idx < 12288) {       // 32 k2 x 128 c
        int i2 = idx - 8192;
        int k2 = i2 >> 7, c = i2 & 127;
        Wdp[i2] = f2h2(Wdst[(2 * k2) * 128 + c], Wdst[(2 * k2 + 1) * 128 + c]);
    }
}

// ---------------------------------------------------------------------------
// z = fp16(h @ W_fc) ; dz = fp16(feat @ W_dst) — both via v_dot2_f32_f16.
// 256 threads/block, 64 nodes/block; grid = 2*nbz (z blocks, then dz blocks).
// Tail: fused dst-histogram (grid-stride, ~2 edges/thread, overlaps drain).
// ---------------------------------------------------------------------------
__global__ __launch_bounds__(256) void k_linear(
        const float* __restrict__ h, const float* __restrict__ feat,
        const unsigned* __restrict__ Wfp, const unsigned* __restrict__ Wdp,
        unsigned short* __restrict__ z_h, unsigned short* __restrict__ dz_h,
        int N, int nbz, const int* __restrict__ dst,
        unsigned* __restrict__ counts, int E) {
    int t  = threadIdx.x;        // 0..255
    int c  = t & 31;             // cols 4c..4c+3
    int j0 = t >> 5;             // 0..7 -> nodes n0 + 8*j0 + jj
    int b  = blockIdx.x;
    bool do_z = (b < nbz);
    int n0 = (do_z ? b : b - nbz) * NB;

    __shared__ uint2 sh[NB * 32];   // 16 KB max (z); dz uses half

    float4 acc[8];
#pragma unroll
    for (int jj = 0; jj < 8; ++jj) acc[jj] = make_float4(0.f, 0.f, 0.f, 0.f);

    if (do_z) {
        // stage h tile fp16: [node][32] uint2 (uint2 = 2 k-pairs = 4 k)
        for (int i = t; i < NB * 32; i += 256) {
            int row = i >> 5, col = i & 31;
            int n = min(n0 + row, N - 1);
            float4 v = ((const float4*)(h + (size_t)n * IN_DIM))[col];
            sh[i] = make_uint2(f2h2(v.x, v.y), f2h2(v.z, v.w));
        }
        __syncthreads();

        const uint4* Wp4 = (const uint4*)Wfp;   // [k2][32] uint4
#pragma unroll 2
        for (int k4 = 0; k4 < 32; ++k4) {
            uint4 wA = Wp4[(size_t)(2 * k4) * 32 + c];       // k-pair 2k4
            uint4 wB = Wp4[(size_t)(2 * k4 + 1) * 32 + c];   // k-pair 2k4+1
#pragma unroll
            for (int jj = 0; jj < 8; ++jj) {
                uint2 q = sh[(j0 * 8 + jj) * 32 + k4];
                acc[jj].x = dot2(q.y, wB.x, dot2(q.x, wA.x, acc[jj].x));
                acc[jj].y = dot2(q.y, wB.y, dot2(q.x, wA.y, acc[jj].y));
                acc[jj].z = dot2(q.y, wB.z, dot2(q.x, wA.z, acc[jj].z));
                acc[jj].w = dot2(q.y, wB.w, dot2(q.x, wA.w, acc[jj].w));
            }
        }
#pragma unroll
        for (int jj = 0; jj < 8; ++jj) {
            int n = n0 + j0 * 8 + jj;
            if (n < N) {
                uint2 pk = make_uint2(f2h2(acc[jj].x, acc[jj].y),
                                      f2h2(acc[jj].z, acc[jj].w));
                ((uint2*)(z_h + (size_t)n * OUT_DIM))[c] = pk;
            }
        }
    } else {
        // stage feat tile fp16: [node][16] uint2
        for (int i = t; i < NB * 16; i += 256) {
            int row = i >> 4, col = i & 15;
            int n = min(n0 + row, N - 1);
            float4 v = ((const float4*)(feat + (size_t)n * FEAT_DIM))[col];
            sh[i] = make_uint2(f2h2(v.x, v.y), f2h2(v.z, v.w));
        }
        __syncthreads();

        const uint4* Wd4 = (const uint4*)Wdp;   // [k2][32] uint4
#pragma unroll 2
        for (int k4 = 0; k4 < 16; ++k4) {
            uint4 wA = Wd4[(size_t)(2 * k4) * 32 + c];
            uint4 wB = Wd4[(size_t)(2 * k4 + 1) * 32 + c];
#pragma unroll
            for (int jj = 0; jj < 8; ++jj) {
                uint2 q = sh[(j0 * 8 + jj) * 16 + k4];
                acc[jj].x = dot2(q.y, wB.x, dot2(q.x, wA.x, acc[jj].x));
                acc[jj].y = dot2(q.y, wB.y, dot2(q.x, wA.y, acc[jj].y));
                acc[jj].z = dot2(q.y, wB.z, dot2(q.x, wA.z, acc[jj].z));
                acc[jj].w = dot2(q.y, wB.w, dot2(q.x, wA.w, acc[jj].w));
            }
        }
#pragma unroll
        for (int jj = 0; jj < 8; ++jj) {
            int n = n0 + j0 * 8 + jj;
            if (n < N) {
                uint2 pk = make_uint2(f2h2(acc[jj].x, acc[jj].y),
                                      f2h2(acc[jj].z, acc[jj].w));
                ((uint2*)(dz_h + (size_t)n * OUT_DIM))[c] = pk;
            }
        }
    }

    // fused dst-histogram tail (~2 edges/thread across the whole grid)
    int gid = b * 256 + t;
    int stride = 2 * nbz * 256;
    for (int i = gid; i < E; i += stride)
        atomicAdd(&counts[dst[i]], 1u);
}

// ---------------------------------------------------------------------------
// CSR build: scan -> bucketed counting sort (k_bin + k_sort)
// ---------------------------------------------------------------------------
__global__ __launch_bounds__(SCH) void k_scan1(const unsigned* __restrict__ counts,
                                               unsigned* __restrict__ partials, int N) {
    int b = blockIdx.x, t = threadIdx.x;
    int idx = b * SCH + t;
    unsigned v = (idx < N) ? counts[idx] : 0u;
#pragma unroll
    for (int off = 32; off; off >>= 1) v += __shfl_xor(v, off);   // wave64 reduce
    __shared__ unsigned sw[SCH / 64];
    if ((t & 63) == 0) sw[t >> 6] = v;
    __syncthreads();
    if (t == 0) {
        unsigned s = 0;
#pragma unroll
        for (int i = 0; i < SCH / 64; ++i) s += sw[i];
        partials[b] = s;
    }
}

__global__ __launch_bounds__(1024) void k_scan2(unsigned* __restrict__ partials, int nblk) {
    __shared__ unsigned s[1024];
    int t = threadIdx.x;
    unsigned v = (t < nblk) ? partials[t] : 0u;
    s[t] = v;
    __syncthreads();
    for (int off = 1; off < 1024; off <<= 1) {
        unsigned u = (t >= off) ? s[t - off] : 0u;
        __syncthreads();
        s[t] += u;
        __syncthreads();
    }
    if (t < nblk) partials[t] = s[t] - v;
}

// also seeds bucket_cursor[b] = offsets[b*256]
__global__ __launch_bounds__(SCH) void k_scan3(const unsigned* __restrict__ counts,
                                               const unsigned* __restrict__ partials,
                                               unsigned* __restrict__ offsets,
                                               unsigned* __restrict__ bucket_cursor, int N) {
    int b = blockIdx.x, t = threadIdx.x;
    int idx = b * SCH + t;
    unsigned v = (idx < N) ? counts[idx] : 0u;
    __shared__ unsigned s[SCH];
    s[t] = v;
    __syncthreads();
    for (int off = 1; off < SCH; off <<= 1) {
        unsigned u = (t >= off) ? s[t - off] : 0u;
        __syncthreads();
        s[t] += u;
        __syncthreads();
    }
    unsigned base = partials[b];
    if (idx < N)  offsets[idx] = base + s[t] - v;
    if (idx == N - 1) offsets[N] = base + s[t];
    if (t == 0) bucket_cursor[b] = base;
}

// counting sort stage 1: bin edges by bucket (dst>>8); payload packed u32:
// src (24 bits) | local-dst (8 bits) << 24.  Line-filling grouped writes.
__global__ __launch_bounds__(256) void k_bin(
        const int* __restrict__ dst, const int* __restrict__ src,
        unsigned* __restrict__ bucket_cursor, unsigned* __restrict__ binned,
        int E, int nbkt) {
    __shared__ unsigned hist[256];
    __shared__ unsigned base[256];
    __shared__ unsigned cur[256];
    int t = threadIdx.x;
    int per = (E + gridDim.x - 1) / gridDim.x;
    int lo = blockIdx.x * per;
    int hi = min(E, lo + per);

    hist[t] = 0;
    cur[t]  = 0;
    __syncthreads();
    for (int i = lo + t; i < hi; i += 256)
        atomicAdd(&hist[dst[i] >> 8], 1u);
    __syncthreads();
    if (t < nbkt) base[t] = atomicAdd(&bucket_cursor[t], hist[t]);
    __syncthreads();
    for (int i = lo + t; i < hi; i += 256) {
        int d = dst[i];
        int bk = d >> 8;
        unsigned slot = base[bk] + atomicAdd(&cur[bk], 1u);
        binned[slot] = (unsigned)src[i] | ((unsigned)(d & 255) << 24);
    }
}

// counting sort stage 2: block b owns dst range [b*256, +256) + its csr window
__global__ __launch_bounds__(256) void k_sort(
        const unsigned* __restrict__ binned, const unsigned* __restrict__ offsets,
        unsigned* __restrict__ csr, int N) {
    __shared__ unsigned off[257];
    __shared__ unsigned cur[256];
    int b = blockIdx.x, t = threadIdx.x;
    int d0 = b << 8;
    int nd = min(N - d0, 256);
    if (t < nd) off[t] = offsets[d0 + t];
    if (t == 0) off[nd] = offsets[d0 + nd];
    cur[t] = 0;
    __syncthreads();
    unsigned lo = off[0], hi = off[nd];
    for (unsigned i = lo + t; i < hi; i += 256) {
        unsigned e = binned[i];
        int ld = (int)(e >> 24);
        unsigned pos = off[ld] + atomicAdd(&cur[ld], 1u);
        csr[pos] = e & 0xFFFFFFu;
    }
}

// ---------------------------------------------------------------------------
// Fused attention + aggregation. One 64-lane wave per node (4 nodes/block).
// 16 lanes per edge; z AND dz rows in FP16 (256 B/row, one uint4/lane).
// Edge dot via v_dot2_f32_f16 chains (4/slot); unpack only for accumulate.
// ---------------------------------------------------------------------------
__global__ __launch_bounds__(256) void k_node(
        const unsigned short* __restrict__ z_h, const unsigned short* __restrict__ dz_h,
        const unsigned* __restrict__ offsets, const unsigned* __restrict__ csr,
        float* __restrict__ out, int N) {
    int lane = threadIdx.x & 63;
    int wv   = threadIdx.x >> 6;          // 0..3
    int g    = lane >> 4;                 // edge slot 0..3
    int l16  = lane & 15;                 // row chunk: dims [8*l16, 8*l16+8)
    int n = blockIdx.x * 4 + wv;
    if (n >= N) return;

    unsigned start = offsets[n];
    int deg = (int)(offsets[n + 1] - start);
    float4* orow = (float4*)(out + (size_t)n * OUT_DIM);
    if (deg == 0) {
        if (g == 0) {
            orow[2 * l16]     = make_float4(0.f, 0.f, 0.f, 0.f);
            orow[2 * l16 + 1] = make_float4(0.f, 0.f, 0.f, 0.f);
        }
        return;
    }

    uint4 dq = ((const uint4*)(dz_h + (size_t)n * OUT_DIM))[l16];  // 8 fp16 dims

    float a[8];
#pragma unroll
    for (int k = 0; k < 8; ++k) a[k] = 0.f;
    float denom = 0.f;

    for (int i = 0; i < deg; i += 8) {
        int eA = i + g;
        int eB = i + 4 + g;
        bool vA = eA < deg;
        bool vB = eB < deg;
        int sA = vA ? (int)csr[start + eA] : 0;
        int sB = vB ? (int)csr[start + eB] : 0;
        uint4 qA = ((const uint4*)(z_h + (size_t)sA * OUT_DIM))[l16];
        uint4 qB = ((const uint4*)(z_h + (size_t)sB * OUT_DIM))[l16];

        float pA = dot2(qA.w, dq.w, dot2(qA.z, dq.z, dot2(qA.y, dq.y, dot2(qA.x, dq.x, 0.f))));
        float pB = dot2(qB.w, dq.w, dot2(qB.z, dq.z, dot2(qB.y, dq.y, dot2(qB.x, dq.x, 0.f))));
#pragma unroll
        for (int off = 1; off <= 8; off <<= 1) {   // reduce within 16-lane group
            pA += __shfl_xor(pA, off);
            pB += __shfl_xor(pB, off);
        }
        float wA = vA ? __expf(pA) : 0.f;
        float wB = vB ? __expf(pB) : 0.f;
        denom += wA + wB;

        float2 zA01 = h2f2(qA.x), zA23 = h2f2(qA.y), zA45 = h2f2(qA.z), zA67 = h2f2(qA.w);
        float2 zB01 = h2f2(qB.x), zB23 = h2f2(qB.y), zB45 = h2f2(qB.z), zB67 = h2f2(qB.w);
        a[0] += wA * zA01.x + wB * zB01.x;  a[1] += wA * zA01.y + wB * zB01.y;
        a[2] += wA * zA23.x + wB * zB23.x;  a[3] += wA * zA23.y + wB * zB23.y;
        a[4] += wA * zA45.x + wB * zB45.x;  a[5] += wA * zA45.y + wB * zB45.y;
        a[6] += wA * zA67.x + wB * zB67.x;  a[7] += wA * zA67.y + wB * zB67.y;
    }

    // fold the 4 edge-groups together (lanes l, l^16, l^32, l^48)
#pragma unroll
    for (int off = 16; off <= 32; off <<= 1) {
#pragma unroll
        for (int k = 0; k < 8; ++k) a[k] += __shfl_xor(a[k], off);
        denom += __shfl_xor(denom, off);
    }

    if (g == 0) {
        float inv = 1.f / denom;
        orow[2 * l16]     = make_float4(a[0] * inv, a[1] * inv, a[2] * inv, a[3] * inv);
        orow[2 * l16 + 1] = make_float4(a[4] * inv, a[5] * inv, a[6] * inv, a[7] * inv);
    }
}

// ---------------------------------------------------------------------------
extern "C" void kernel_launch(void* const* d_in, const int* in_sizes, int n_in,
                              void* d_out, int out_size, void* d_ws, size_t ws_size,
                              hipStream_t stream) {
    const float* h    = (const float*)d_in[0];
    const float* feat = (const float*)d_in[1];
    const float* Wfc  = (const float*)d_in[2];
    const float* Wdst = (const float*)d_in[3];
    const int*   src  = (const int*)d_in[4];
    const int*   dst  = (const int*)d_in[5];
    float*       out  = (float*)d_out;

    int N = in_sizes[0] / IN_DIM;
    int E = in_sizes[4];

    char* ws = (char*)d_ws;
    unsigned short* z_h  = (unsigned short*)ws; ws += (size_t)N * OUT_DIM * sizeof(unsigned short);
    unsigned short* dz_h = (unsigned short*)ws; ws += (size_t)N * OUT_DIM * sizeof(unsigned short);
    unsigned* Wfp      = (unsigned*)ws; ws += (size_t)8192 * sizeof(unsigned);
    unsigned* Wdp      = (unsigned*)ws; ws += (size_t)4096 * sizeof(unsigned);
    unsigned* binned   = (unsigned*)ws; ws += (size_t)E * sizeof(unsigned);
    unsigned* counts   = (unsigned*)ws; ws += (size_t)N * sizeof(unsigned);
    unsigned* offsets  = (unsigned*)ws; ws += (size_t)(N + 1) * sizeof(unsigned);
    unsigned* partials = (unsigned*)ws; ws += (size_t)1024 * sizeof(unsigned);
    unsigned* bcursor  = (unsigned*)ws; ws += (size_t)1024 * sizeof(unsigned);
    unsigned* csr      = (unsigned*)ws;

    int nbz  = (N + NB - 1) / NB;       // 782
    int nblk = (N + SCH - 1) / SCH;     // 196 buckets

    hipMemsetAsync(counts, 0, (size_t)N * sizeof(unsigned), stream);

    k_wt     <<<48, 256, 0, stream>>>(Wfc, Wdst, Wfp, Wdp);
    k_linear <<<2 * nbz, 256, 0, stream>>>(h, feat, Wfp, Wdp, z_h, dz_h, N, nbz,
                                           dst, counts, E);
    k_scan1  <<<nblk, SCH, 0, stream>>>(counts, partials, N);
    k_scan2  <<<1, 1024, 0, stream>>>(partials, nblk);
    k_scan3  <<<nblk, SCH, 0, stream>>>(counts, partials, offsets, bcursor, N);
    k_bin    <<<512, 256, 0, stream>>>(dst, src, bcursor, binned, E, nblk);
    k_sort   <<<nblk, 256, 0, stream>>>(binned, offsets, csr, N);
    k_node   <<<(N + 3) / 4, 256, 0, stream>>>(z_h, dz_h, offsets, csr, out, N);
}